// Round 4
// baseline (52.054 us; speedup 1.0000x reference)
//
#include <hip/hip_runtime.h>

// B=32, R=3136 (=56*56), O=20, D=32. Memory-bound: ~294 MB traffic.
// R1 structure (50.1 us) + nontemporal streaming hints (form read once,
// outputs written once -> bypass L2/L3 allocation).
#define NB 32
#define NR 3136
#define NO 20
#define ND 32
#define RPB 16            // rays per block
#define BLOCK (RPB * 32)  // 512

typedef float f4v __attribute__((ext_vector_type(4)));

__global__ __launch_bounds__(BLOCK) void ray_composite(
    const float* __restrict__ form,    // [B,R,O,D]
    const float* __restrict__ depth,   // [B,R,O]
    const float* __restrict__ trans,   // [B,R,O]
    float* __restrict__ out_res,       // [B,D,H,W]
    float* __restrict__ out_pond)      // [B,R,O]
{
  __shared__ float res_lds[RPB][36];     // pad 32->36: float4-aligned, 2-way max
  __shared__ float pond_lds[RPB * NO];

  const int t    = threadIdx.x;
  const int rib  = t >> 5;
  const int lane = t & 31;
  const int ray0 = blockIdx.x * RPB;
  const int ray  = ray0 + rib;
  const int b    = ray0 / NR;
  const int r0   = ray0 - b * NR;

  // ---- phase 1: ponderation (lane o<20 owns object o of its ray) ----
  float d_o = 0.f, t_o = 0.f;
  if (lane < NO) {
    d_o = depth[(size_t)ray * NO + lane];
    t_o = trans[(size_t)ray * NO + lane];
  }
  float acc = 0.f;
#pragma unroll
  for (int j = 0; j < NO; ++j) {
    const float dj = __shfl(d_o, j, 32);
    const float tj = __shfl(t_o, j, 32);
    const float s  = 1.f / (1.f + __expf(-1000.f * (d_o - dj)));
    if (j != lane) acc += tj * s;
  }
  float pond = __expf(acc) * (1.f - __expf(t_o));
  if (lane >= NO) pond = 0.f;
  if (lane < NO) pond_lds[rib * NO + lane] = pond;

  // ---- phase 2: res[d] = sum_o pond[o]*form[o][d], NT float4 loads ----
  const int c  = lane & 7;
  const int og = lane >> 3;
  const float* fbase = form + (size_t)ray * (NO * ND);
  f4v accv = {0.f, 0.f, 0.f, 0.f};
#pragma unroll
  for (int k = 0; k < 5; ++k) {
    const int o = og + 4 * k;
    const float p = __shfl(pond, o, 32);
    const f4v v = __builtin_nontemporal_load(
        reinterpret_cast<const f4v*>(fbase + o * ND + c * 4));
    accv += p * v;
  }
#pragma unroll
  for (int m = 8; m <= 16; m <<= 1) {   // reduce across the 4 row-groups
    accv.x += __shfl_xor(accv.x, m, 32);
    accv.y += __shfl_xor(accv.y, m, 32);
    accv.z += __shfl_xor(accv.z, m, 32);
    accv.w += __shfl_xor(accv.w, m, 32);
  }
  if (lane < 8)
    *reinterpret_cast<f4v*>(&res_lds[rib][lane * 4]) = accv;

  __syncthreads();

  // ---- phase 3: coalesced NT stores ----
  {
    const int d  = t >> 4;
    const int rr = t & 15;
    __builtin_nontemporal_store(
        res_lds[rr][d],
        out_res + (size_t)b * (ND * NR) + (size_t)d * NR + r0 + rr);
  }
  if (t < RPB * NO)
    __builtin_nontemporal_store(pond_lds[t], out_pond + (size_t)ray0 * NO + t);
}

extern "C" void kernel_launch(void* const* d_in, const int* in_sizes, int n_in,
                              void* d_out, int out_size, void* d_ws, size_t ws_size,
                              hipStream_t stream) {
  const float* form  = (const float*)d_in[0];
  const float* depth = (const float*)d_in[1];
  const float* trans = (const float*)d_in[2];

  float* out_res  = (float*)d_out;
  float* out_pond = out_res + (size_t)NB * ND * NR;

  dim3 grid((NB * NR) / RPB);   // 6272
  dim3 block(BLOCK);            // 512
  ray_composite<<<grid, block, 0, stream>>>(form, depth, trans, out_res, out_pond);
}